// Round 21
// baseline (48.924 us; speedup 1.0000x reference)
//
#include <hip/hip_runtime.h>

#define BSES 64
#define EDIM 128
#define HDIM 128
#define KSCALE 2.8853900817779268f  // 2*log2(e): exp(2x) = exp2(KSCALE*x)

typedef float v2f __attribute__((ext_vector_type(2)));

__device__ __forceinline__ float fexp2(float x) {
#if __has_builtin(__builtin_amdgcn_exp2f)
  return __builtin_amdgcn_exp2f(x);
#else
  return exp2f(x);
#endif
}
__device__ __forceinline__ float frcp(float x) {
#if __has_builtin(__builtin_amdgcn_rcpf)
  return __builtin_amdgcn_rcpf(x);
#else
  return 1.0f / x;
#endif
}
__device__ __forceinline__ v2f mkv2(float a, float b) {
  v2f r;
  r.x = a;
  r.y = b;
  return r;
}

// 8-term batched reciprocal sum via PACKED f32 (R20-proven).
// 13 pk + 2 rcp + 2 scalar fma per 8 elems.
__device__ __forceinline__ float g4pk8(float4 s0, float4 s1, float4 w0,
                                       float4 w1, float4 v0, float4 v1,
                                       float acc) {
  const v2f one = {1.f, 1.f};
  v2f s01 = mkv2(s0.x, s0.y), s23 = mkv2(s0.z, s0.w);
  v2f s45 = mkv2(s1.x, s1.y), s67 = mkv2(s1.z, s1.w);
  v2f w01 = mkv2(w0.x, w0.y), w23 = mkv2(w0.z, w0.w);
  v2f w45 = mkv2(w1.x, w1.y), w67 = mkv2(w1.z, w1.w);
  v2f v01 = mkv2(v0.x, v0.y), v23 = mkv2(v0.z, v0.w);
  v2f v45 = mkv2(v1.x, v1.y), v67 = mkv2(v1.z, v1.w);
  v2f x01 = __builtin_elementwise_fma(s01, v01, one);
  v2f x23 = __builtin_elementwise_fma(s23, v23, one);
  v2f x45 = __builtin_elementwise_fma(s45, v45, one);
  v2f x67 = __builtin_elementwise_fma(s67, v67, one);
  v2f p03 = x01 * x23;
  v2f p47 = x45 * x67;
  v2f n03 = __builtin_elementwise_fma(w23, x01, w01 * x23);
  v2f n47 = __builtin_elementwise_fma(w67, x45, w45 * x67);
  v2f num = __builtin_elementwise_fma(n47, p03, n03 * p47);
  v2f den = p03 * p47;
  acc = fmaf(num.x, frcp(den.x), acc);
  acc = fmaf(num.y, frcp(den.y), acc);
  return acc;
}

// Session projection (R12/R13/R20-proven, verbatim).
// esp4 PACKED [h/4][b][4]; plus C = sum(W3)+b3.
__global__ __launch_bounds__(256) void taa_esp(
    const float* __restrict__ sess, const float* __restrict__ W1,
    const float* __restrict__ b1, const float* __restrict__ W3,
    const float* __restrict__ b3, float* __restrict__ esp4,
    float* __restrict__ C_out) {
  int t = blockIdx.x * 256 + threadIdx.x;
  if (t < BSES * HDIM) {
    int b = t >> 7, h = t & 127;
    const float* srow = sess + b * EDIM;
    float acc = 0.f;
#pragma unroll 4
    for (int e = 0; e < EDIM; ++e)
      acc = fmaf(srow[e], W1[e * HDIM + h], acc);
    esp4[(h >> 2) * 256 + b * 4 + (h & 3)] = fexp2((acc + b1[h]) * KSCALE);
  }
  if (t == 0) {
    float s = b3[0];
    for (int i = 0; i < HDIM; ++i) s += W3[i];
    *C_out = s;
  }
}

// Score 4 targets (rows t0..t0+3 of the LDS et tile, row stride 128) for
// this lane's session (R20-proven packed score4, verbatim).
__device__ __forceinline__ void score4(
    const float* __restrict__ et, int t0, int lane,
    const float* __restrict__ esp4, const float* __restrict__ w3,
    float acc[4]) {
  const float* base = et + t0 * HDIM;
#pragma unroll 2
  for (int c = 0; c < 8; ++c) {
    float4 sp[4];
#pragma unroll
    for (int k = 0; k < 4; ++k)
      sp[k] = *(const float4*)(esp4 + ((c << 2) + k) * 256 + (lane << 2));
    float4 wq[4];
#pragma unroll
    for (int k = 0; k < 4; ++k)
      wq[k] = *(const float4*)(w3 + (c << 4) + k * 4);  // uniform
#pragma unroll
    for (int t = 0; t < 4; ++t) {
      const float* rp = base + t * HDIM + (c << 4);
      float4 v0 = *(const float4*)(rp + 0);  // ds_read_b128 broadcast
      float4 v1 = *(const float4*)(rp + 4);
      float4 v2 = *(const float4*)(rp + 8);
      float4 v3 = *(const float4*)(rp + 12);
      acc[t] = g4pk8(sp[0], sp[1], wq[0], wq[1], v0, v1, acc[t]);
      acc[t] = g4pk8(sp[2], sp[3], wq[2], wq[3], v2, v3, acc[t]);
    }
  }
}

// Fused per 32-target tile, 256 threads. CHANGE vs R20: NO emb LDS staging
// -- the GEMM reads emb directly from global (2-distinct-address broadcast
// dwordx4 per wave-instr; each 16B segment read exactly once per block).
// Removes 528 of 1568 LDS b128 ops/block (-34% on the shared per-CU LDS
// pipe) and one barrier. P2: GEMM + exp2 -> et[32][128] LDS. P3: packed
// score4 x2 (rows wv*4 and wv*4+16).
// score[b][n] = C - 2 * sum_h w3[h] * rcp(fma(esp[b][h], etp[n][h], 1))
__global__ __launch_bounds__(256) void taa_fused(
    const float* __restrict__ emb, const float* __restrict__ W2,
    const float* __restrict__ b2, const float* __restrict__ esp4,
    const float* __restrict__ w3, const float* __restrict__ Cptr,
    float* __restrict__ out, int N) {
  __shared__ float et[32 * HDIM];  // exp2(tp') tile (16 KB, only LDS)
  const int nb = blockIdx.x * 32;

  // Phase 2: GEMM + exp2 -> et (LDS). Thread = 4 rows x 4 h. emb direct.
  {
    const int h4 = (threadIdx.x & 31) * 4;
    const int rg = threadIdx.x >> 5;  // 8 groups of 4 rows
    const float* er0 = emb + (size_t)min(nb + rg * 4 + 0, N - 1) * EDIM;
    const float* er1 = emb + (size_t)min(nb + rg * 4 + 1, N - 1) * EDIM;
    const float* er2 = emb + (size_t)min(nb + rg * 4 + 2, N - 1) * EDIM;
    const float* er3 = emb + (size_t)min(nb + rg * 4 + 3, N - 1) * EDIM;
    float acc[4][4];
#pragma unroll
    for (int j = 0; j < 4; ++j)
#pragma unroll
      for (int q = 0; q < 4; ++q) acc[j][q] = 0.f;
#pragma unroll 2
    for (int e = 0; e < EDIM; e += 4) {
      float4 w[4];
#pragma unroll
      for (int q = 0; q < 4; ++q)
        w[q] = *(const float4*)(W2 + (size_t)(e + q) * HDIM + h4);
      float4 em0 = *(const float4*)(er0 + e);  // global broadcast (2 addr/wave)
      float4 em1 = *(const float4*)(er1 + e);
      float4 em2 = *(const float4*)(er2 + e);
      float4 em3 = *(const float4*)(er3 + e);
#define ROW(em, j)                                                          \
      acc[j][0] = fmaf(em.x, w[0].x, acc[j][0]);                            \
      acc[j][1] = fmaf(em.x, w[0].y, acc[j][1]);                            \
      acc[j][2] = fmaf(em.x, w[0].z, acc[j][2]);                            \
      acc[j][3] = fmaf(em.x, w[0].w, acc[j][3]);                            \
      acc[j][0] = fmaf(em.y, w[1].x, acc[j][0]);                            \
      acc[j][1] = fmaf(em.y, w[1].y, acc[j][1]);                            \
      acc[j][2] = fmaf(em.y, w[1].z, acc[j][2]);                            \
      acc[j][3] = fmaf(em.y, w[1].w, acc[j][3]);                            \
      acc[j][0] = fmaf(em.z, w[2].x, acc[j][0]);                            \
      acc[j][1] = fmaf(em.z, w[2].y, acc[j][1]);                            \
      acc[j][2] = fmaf(em.z, w[2].z, acc[j][2]);                            \
      acc[j][3] = fmaf(em.z, w[2].w, acc[j][3]);                            \
      acc[j][0] = fmaf(em.w, w[3].x, acc[j][0]);                            \
      acc[j][1] = fmaf(em.w, w[3].y, acc[j][1]);                            \
      acc[j][2] = fmaf(em.w, w[3].z, acc[j][2]);                            \
      acc[j][3] = fmaf(em.w, w[3].w, acc[j][3]);
      ROW(em0, 0)
      ROW(em1, 1)
      ROW(em2, 2)
      ROW(em3, 3)
#undef ROW
    }
    float4 bb2 = *(const float4*)(b2 + h4);
#pragma unroll
    for (int j = 0; j < 4; ++j) {
      int nr = rg * 4 + j;
      float4 o;
      o.x = fexp2((acc[j][0] + bb2.x) * KSCALE);
      o.y = fexp2((acc[j][1] + bb2.y) * KSCALE);
      o.z = fexp2((acc[j][2] + bb2.z) * KSCALE);
      o.w = fexp2((acc[j][3] + bb2.w) * KSCALE);
      *(float4*)&et[nr * HDIM + h4] = o;  // wave-contiguous, conflict-free
    }
  }
  __syncthreads();

  // Phase 3: scoring. lane = session.
  const int lane = threadIdx.x & 63;
  const int wv = threadIdx.x >> 6;  // 0..3
  float acc0[4] = {0.f, 0.f, 0.f, 0.f};
  float acc1[4] = {0.f, 0.f, 0.f, 0.f};
  score4(et, wv * 4, lane, esp4, w3, acc0);
  score4(et, wv * 4 + 16, lane, esp4, w3, acc1);

  const float Cv = *Cptr;  // uniform
  const int n0 = nb + wv * 4;
  const int n1 = n0 + 16;
  float4 res0, res1;
  res0.x = fmaf(-2.f, acc0[0], Cv);
  res0.y = fmaf(-2.f, acc0[1], Cv);
  res0.z = fmaf(-2.f, acc0[2], Cv);
  res0.w = fmaf(-2.f, acc0[3], Cv);
  res1.x = fmaf(-2.f, acc1[0], Cv);
  res1.y = fmaf(-2.f, acc1[1], Cv);
  res1.z = fmaf(-2.f, acc1[2], Cv);
  res1.w = fmaf(-2.f, acc1[3], Cv);
  float* po = out + (size_t)lane * N;
  if (n0 + 3 < N) {
    *(float4*)(po + n0) = res0;
  } else {
    float r4[4] = {res0.x, res0.y, res0.z, res0.w};
    for (int i = 0; i < 4 && n0 + i < N; ++i) po[n0 + i] = r4[i];
  }
  if (n1 + 3 < N) {
    *(float4*)(po + n1) = res1;
  } else {
    float r4[4] = {res1.x, res1.y, res1.z, res1.w};
    for (int i = 0; i < 4 && n1 + i < N; ++i) po[n1 + i] = r4[i];
  }
}

extern "C" void kernel_launch(void* const* d_in, const int* in_sizes, int n_in,
                              void* d_out, int out_size, void* d_ws, size_t ws_size,
                              hipStream_t stream) {
  const float* sess = (const float*)d_in[0];
  const float* emb  = (const float*)d_in[1];
  const float* W1   = (const float*)d_in[2];
  const float* b1   = (const float*)d_in[3];
  const float* W2   = (const float*)d_in[4];
  const float* b2   = (const float*)d_in[5];
  const float* W3   = (const float*)d_in[6];
  const float* b3   = (const float*)d_in[7];
  float* out = (float*)d_out;
  const int B = in_sizes[0] / EDIM;   // 64
  const int N = in_sizes[1] / EDIM;   // 20000

  float* esp4 = (float*)d_ws;                     // B*128 floats (packed)
  float* Cp   = esp4 + (size_t)BSES * HDIM;       // 1 float

  taa_esp<<<(B * HDIM + 255) / 256, 256, 0, stream>>>(sess, W1, b1, W3, b3,
                                                      esp4, Cp);
  taa_fused<<<(N + 31) / 32, 256, 0, stream>>>(emb, W2, b2, esp4, W3, Cp,
                                               out, N);
}

// Round 22
// 41.781 us; speedup vs baseline: 1.1710x; 1.1710x over previous
//
#include <hip/hip_runtime.h>

#define BSES 64
#define EDIM 128
#define HDIM 128
#define KSCALE 2.8853900817779268f  // 2*log2(e): exp(2x) = exp2(KSCALE*x)

typedef float v2f __attribute__((ext_vector_type(2)));

__device__ __forceinline__ float fexp2(float x) {
#if __has_builtin(__builtin_amdgcn_exp2f)
  return __builtin_amdgcn_exp2f(x);
#else
  return exp2f(x);
#endif
}
__device__ __forceinline__ float frcp(float x) {
#if __has_builtin(__builtin_amdgcn_rcpf)
  return __builtin_amdgcn_rcpf(x);
#else
  return 1.0f / x;
#endif
}
__device__ __forceinline__ v2f mkv2(float a, float b) {
  v2f r;
  r.x = a;
  r.y = b;
  return r;
}

// 8-term batched reciprocal sum via PACKED f32 (R20-proven).
// 13 pk + 2 rcp + 2 scalar fma per 8 elems.
__device__ __forceinline__ float g4pk8(float4 s0, float4 s1, float4 w0,
                                       float4 w1, float4 v0, float4 v1,
                                       float acc) {
  const v2f one = {1.f, 1.f};
  v2f s01 = mkv2(s0.x, s0.y), s23 = mkv2(s0.z, s0.w);
  v2f s45 = mkv2(s1.x, s1.y), s67 = mkv2(s1.z, s1.w);
  v2f w01 = mkv2(w0.x, w0.y), w23 = mkv2(w0.z, w0.w);
  v2f w45 = mkv2(w1.x, w1.y), w67 = mkv2(w1.z, w1.w);
  v2f v01 = mkv2(v0.x, v0.y), v23 = mkv2(v0.z, v0.w);
  v2f v45 = mkv2(v1.x, v1.y), v67 = mkv2(v1.z, v1.w);
  v2f x01 = __builtin_elementwise_fma(s01, v01, one);
  v2f x23 = __builtin_elementwise_fma(s23, v23, one);
  v2f x45 = __builtin_elementwise_fma(s45, v45, one);
  v2f x67 = __builtin_elementwise_fma(s67, v67, one);
  v2f p03 = x01 * x23;
  v2f p47 = x45 * x67;
  v2f n03 = __builtin_elementwise_fma(w23, x01, w01 * x23);
  v2f n47 = __builtin_elementwise_fma(w67, x45, w45 * x67);
  v2f num = __builtin_elementwise_fma(n47, p03, n03 * p47);
  v2f den = p03 * p47;
  acc = fmaf(num.x, frcp(den.x), acc);
  acc = fmaf(num.y, frcp(den.y), acc);
  return acc;
}

// Session projection (proven, verbatim). esp4 PACKED [h/4][b][4]; plus C.
__global__ __launch_bounds__(256) void taa_esp(
    const float* __restrict__ sess, const float* __restrict__ W1,
    const float* __restrict__ b1, const float* __restrict__ W3,
    const float* __restrict__ b3, float* __restrict__ esp4,
    float* __restrict__ C_out) {
  int t = blockIdx.x * 256 + threadIdx.x;
  if (t < BSES * HDIM) {
    int b = t >> 7, h = t & 127;
    const float* srow = sess + b * EDIM;
    float acc = 0.f;
#pragma unroll 4
    for (int e = 0; e < EDIM; ++e)
      acc = fmaf(srow[e], W1[e * HDIM + h], acc);
    esp4[(h >> 2) * 256 + b * 4 + (h & 3)] = fexp2((acc + b1[h]) * KSCALE);
  }
  if (t == 0) {
    float s = b3[0];
    for (int i = 0; i < HDIM; ++i) s += W3[i];
    *C_out = s;
  }
}

// Score 4 targets (rows t0..t0+3) x TWO sessions (2*sp2, 2*sp2+1).
// Halves per-thread et ds_reads vs R20 (128 vs 256); sp VMEM doubles but
// is coalesced on the (uncontended) VMEM pipe. et reads are 2-address
// wave broadcasts (rows t, t+16) -> 2-way = free (m136).
__device__ __forceinline__ void score4x2(
    const float* __restrict__ et, int t0, int sp2,
    const float* __restrict__ esp4, const float* __restrict__ w3,
    float accA[4], float accB[4]) {
  const float* base = et + t0 * HDIM;
#pragma unroll 2
  for (int c = 0; c < 8; ++c) {
    float4 spA[4], spB[4];
#pragma unroll
    for (int k = 0; k < 4; ++k) {
      const float* p = esp4 + ((c << 2) + k) * 256 + (sp2 << 3);
      spA[k] = *(const float4*)p;        // session 2*sp2
      spB[k] = *(const float4*)(p + 4);  // session 2*sp2+1
    }
    float4 wq[4];
#pragma unroll
    for (int k = 0; k < 4; ++k)
      wq[k] = *(const float4*)(w3 + (c << 4) + k * 4);  // uniform
#pragma unroll
    for (int t = 0; t < 4; ++t) {
      const float* rp = base + t * HDIM + (c << 4);
      float4 v0 = *(const float4*)(rp + 0);  // 2-addr ds_read broadcast
      float4 v1 = *(const float4*)(rp + 4);
      float4 v2 = *(const float4*)(rp + 8);
      float4 v3 = *(const float4*)(rp + 12);
      accA[t] = g4pk8(spA[0], spA[1], wq[0], wq[1], v0, v1, accA[t]);
      accA[t] = g4pk8(spA[2], spA[3], wq[2], wq[3], v2, v3, accA[t]);
      accB[t] = g4pk8(spB[0], spB[1], wq[0], wq[1], v0, v1, accB[t]);
      accB[t] = g4pk8(spB[2], spB[3], wq[2], wq[3], v2, v3, accB[t]);
    }
  }
}

// Fused per 32-target tile, 256 threads (R20-proven P1+P2 verbatim).
// P3 re-partitioned: lane&31 = session-pair, lane>>5 = target-half;
// thread = 2 sessions x 4 targets (halves the dominant et LDS-pipe term).
// score[b][n] = C - 2 * sum_h w3[h] * rcp(fma(esp[b][h], etp[n][h], 1))
__global__ __launch_bounds__(256) void taa_fused(
    const float* __restrict__ emb, const float* __restrict__ W2,
    const float* __restrict__ b2, const float* __restrict__ esp4,
    const float* __restrict__ w3, const float* __restrict__ Cptr,
    float* __restrict__ out, int N) {
  __shared__ float sm[32][132];       // emb tile, padded stride
  __shared__ float et[32 * HDIM];     // exp2(tp') tile
  const int nb = blockIdx.x * 32;

  // Phase 1: stage emb tile (coalesced float4).
  for (int k = threadIdx.x; k < 32 * 32; k += 256) {
    int r = k >> 5, c4 = k & 31;
    float4 v = make_float4(0.f, 0.f, 0.f, 0.f);
    if (nb + r < N) v = ((const float4*)(emb + (size_t)(nb + r) * EDIM))[c4];
    *(float4*)&sm[r][c4 * 4] = v;
  }
  __syncthreads();

  // Phase 2: GEMM + exp2 -> et (LDS). Thread = 4 rows x 4 h (R20 verbatim).
  {
    const int h4 = (threadIdx.x & 31) * 4;
    const int rg = threadIdx.x >> 5;  // 8 groups of 4 rows
    float acc[4][4];
#pragma unroll
    for (int j = 0; j < 4; ++j)
#pragma unroll
      for (int q = 0; q < 4; ++q) acc[j][q] = 0.f;
    for (int e = 0; e < EDIM; e += 4) {
      float4 w[4];
#pragma unroll
      for (int q = 0; q < 4; ++q)
        w[q] = *(const float4*)(W2 + (size_t)(e + q) * HDIM + h4);
#pragma unroll
      for (int j = 0; j < 4; ++j) {
        float4 em = *(const float4*)&sm[rg * 4 + j][e];
        acc[j][0] = fmaf(em.x, w[0].x, acc[j][0]);
        acc[j][1] = fmaf(em.x, w[0].y, acc[j][1]);
        acc[j][2] = fmaf(em.x, w[0].z, acc[j][2]);
        acc[j][3] = fmaf(em.x, w[0].w, acc[j][3]);
        acc[j][0] = fmaf(em.y, w[1].x, acc[j][0]);
        acc[j][1] = fmaf(em.y, w[1].y, acc[j][1]);
        acc[j][2] = fmaf(em.y, w[1].z, acc[j][2]);
        acc[j][3] = fmaf(em.y, w[1].w, acc[j][3]);
        acc[j][0] = fmaf(em.z, w[2].x, acc[j][0]);
        acc[j][1] = fmaf(em.z, w[2].y, acc[j][1]);
        acc[j][2] = fmaf(em.z, w[2].z, acc[j][2]);
        acc[j][3] = fmaf(em.z, w[2].w, acc[j][3]);
        acc[j][0] = fmaf(em.w, w[3].x, acc[j][0]);
        acc[j][1] = fmaf(em.w, w[3].y, acc[j][1]);
        acc[j][2] = fmaf(em.w, w[3].z, acc[j][2]);
        acc[j][3] = fmaf(em.w, w[3].w, acc[j][3]);
      }
    }
    float4 bb2 = *(const float4*)(b2 + h4);
#pragma unroll
    for (int j = 0; j < 4; ++j) {
      int nr = rg * 4 + j;
      float4 o;
      o.x = fexp2((acc[j][0] + bb2.x) * KSCALE);
      o.y = fexp2((acc[j][1] + bb2.y) * KSCALE);
      o.z = fexp2((acc[j][2] + bb2.z) * KSCALE);
      o.w = fexp2((acc[j][3] + bb2.w) * KSCALE);
      *(float4*)&et[nr * HDIM + h4] = o;  // wave-contiguous, conflict-free
    }
  }
  __syncthreads();

  // Phase 3: scoring. lane&31 = session-pair, lane>>5 = target-half.
  const int lane = threadIdx.x & 63;
  const int wv = threadIdx.x >> 6;  // 0..3
  const int sp2 = lane & 31;        // sessions 2*sp2, 2*sp2+1
  const int th = lane >> 5;         // target half (0 -> rows 0-15, 1 -> 16-31)
  const int t0 = wv * 4 + th * 16;
  float accA[4] = {0.f, 0.f, 0.f, 0.f};
  float accB[4] = {0.f, 0.f, 0.f, 0.f};
  score4x2(et, t0, sp2, esp4, w3, accA, accB);

  const float Cv = *Cptr;  // uniform
  const int n0 = nb + t0;
  const int sA = sp2 * 2, sB = sA + 1;
  float4 resA, resB;
  resA.x = fmaf(-2.f, accA[0], Cv);
  resA.y = fmaf(-2.f, accA[1], Cv);
  resA.z = fmaf(-2.f, accA[2], Cv);
  resA.w = fmaf(-2.f, accA[3], Cv);
  resB.x = fmaf(-2.f, accB[0], Cv);
  resB.y = fmaf(-2.f, accB[1], Cv);
  resB.z = fmaf(-2.f, accB[2], Cv);
  resB.w = fmaf(-2.f, accB[3], Cv);
  if (n0 + 3 < N) {
    *(float4*)(out + (size_t)sA * N + n0) = resA;
    *(float4*)(out + (size_t)sB * N + n0) = resB;
  } else {
    float rA[4] = {resA.x, resA.y, resA.z, resA.w};
    float rB[4] = {resB.x, resB.y, resB.z, resB.w};
    for (int i = 0; i < 4 && n0 + i < N; ++i) {
      out[(size_t)sA * N + n0 + i] = rA[i];
      out[(size_t)sB * N + n0 + i] = rB[i];
    }
  }
}

extern "C" void kernel_launch(void* const* d_in, const int* in_sizes, int n_in,
                              void* d_out, int out_size, void* d_ws, size_t ws_size,
                              hipStream_t stream) {
  const float* sess = (const float*)d_in[0];
  const float* emb  = (const float*)d_in[1];
  const float* W1   = (const float*)d_in[2];
  const float* b1   = (const float*)d_in[3];
  const float* W2   = (const float*)d_in[4];
  const float* b2   = (const float*)d_in[5];
  const float* W3   = (const float*)d_in[6];
  const float* b3   = (const float*)d_in[7];
  float* out = (float*)d_out;
  const int B = in_sizes[0] / EDIM;   // 64
  const int N = in_sizes[1] / EDIM;   // 20000

  float* esp4 = (float*)d_ws;                     // B*128 floats (packed)
  float* Cp   = esp4 + (size_t)BSES * HDIM;       // 1 float

  taa_esp<<<(B * HDIM + 255) / 256, 256, 0, stream>>>(sess, W1, b1, W3, b3,
                                                      esp4, Cp);
  taa_fused<<<(N + 31) / 32, 256, 0, stream>>>(emb, W2, b2, esp4, W3, Cp,
                                               out, N);
}

// Round 23
// 39.523 us; speedup vs baseline: 1.2379x; 1.0571x over previous
//
#include <hip/hip_runtime.h>

#define BSES 64
#define EDIM 128
#define HDIM 128
#define NT 40  // targets per block: 500 blocks = 1.95/CU (balanced grid)
#define KSCALE 2.8853900817779268f  // 2*log2(e): exp(2x) = exp2(KSCALE*x)

typedef float v2f __attribute__((ext_vector_type(2)));

__device__ __forceinline__ float fexp2(float x) {
#if __has_builtin(__builtin_amdgcn_exp2f)
  return __builtin_amdgcn_exp2f(x);
#else
  return exp2f(x);
#endif
}
__device__ __forceinline__ float frcp(float x) {
#if __has_builtin(__builtin_amdgcn_rcpf)
  return __builtin_amdgcn_rcpf(x);
#else
  return 1.0f / x;
#endif
}
__device__ __forceinline__ v2f mkv2(float a, float b) {
  v2f r;
  r.x = a;
  r.y = b;
  return r;
}

// 8-term batched reciprocal sum via PACKED f32 (R20/R22-proven).
__device__ __forceinline__ float g4pk8(float4 s0, float4 s1, float4 w0,
                                       float4 w1, float4 v0, float4 v1,
                                       float acc) {
  const v2f one = {1.f, 1.f};
  v2f s01 = mkv2(s0.x, s0.y), s23 = mkv2(s0.z, s0.w);
  v2f s45 = mkv2(s1.x, s1.y), s67 = mkv2(s1.z, s1.w);
  v2f w01 = mkv2(w0.x, w0.y), w23 = mkv2(w0.z, w0.w);
  v2f w45 = mkv2(w1.x, w1.y), w67 = mkv2(w1.z, w1.w);
  v2f v01 = mkv2(v0.x, v0.y), v23 = mkv2(v0.z, v0.w);
  v2f v45 = mkv2(v1.x, v1.y), v67 = mkv2(v1.z, v1.w);
  v2f x01 = __builtin_elementwise_fma(s01, v01, one);
  v2f x23 = __builtin_elementwise_fma(s23, v23, one);
  v2f x45 = __builtin_elementwise_fma(s45, v45, one);
  v2f x67 = __builtin_elementwise_fma(s67, v67, one);
  v2f p03 = x01 * x23;
  v2f p47 = x45 * x67;
  v2f n03 = __builtin_elementwise_fma(w23, x01, w01 * x23);
  v2f n47 = __builtin_elementwise_fma(w67, x45, w45 * x67);
  v2f num = __builtin_elementwise_fma(n47, p03, n03 * p47);
  v2f den = p03 * p47;
  acc = fmaf(num.x, frcp(den.x), acc);
  acc = fmaf(num.y, frcp(den.y), acc);
  return acc;
}

// Session projection (proven, verbatim). esp4 PACKED [h/4][b][4]; plus C.
__global__ __launch_bounds__(256) void taa_esp(
    const float* __restrict__ sess, const float* __restrict__ W1,
    const float* __restrict__ b1, const float* __restrict__ W3,
    const float* __restrict__ b3, float* __restrict__ esp4,
    float* __restrict__ C_out) {
  int t = blockIdx.x * 256 + threadIdx.x;
  if (t < BSES * HDIM) {
    int b = t >> 7, h = t & 127;
    const float* srow = sess + b * EDIM;
    float acc = 0.f;
#pragma unroll 4
    for (int e = 0; e < EDIM; ++e)
      acc = fmaf(srow[e], W1[e * HDIM + h], acc);
    esp4[(h >> 2) * 256 + b * 4 + (h & 3)] = fexp2((acc + b1[h]) * KSCALE);
  }
  if (t == 0) {
    float s = b3[0];
    for (int i = 0; i < HDIM; ++i) s += W3[i];
    *C_out = s;
  }
}

// Score 5 targets (rows t0..t0+4) x TWO sessions (R22-proven pattern,
// target count 4 -> 5). et reads: 2-addr wave broadcasts (free, m136).
__device__ __forceinline__ void score5x2(
    const float* __restrict__ et, int t0, int sp2,
    const float* __restrict__ esp4, const float* __restrict__ w3,
    float accA[5], float accB[5]) {
  const float* base = et + t0 * HDIM;
#pragma unroll 2
  for (int c = 0; c < 8; ++c) {
    float4 spA[4], spB[4];
#pragma unroll
    for (int k = 0; k < 4; ++k) {
      const float* p = esp4 + ((c << 2) + k) * 256 + (sp2 << 3);
      spA[k] = *(const float4*)p;        // session 2*sp2
      spB[k] = *(const float4*)(p + 4);  // session 2*sp2+1
    }
    float4 wq[4];
#pragma unroll
    for (int k = 0; k < 4; ++k)
      wq[k] = *(const float4*)(w3 + (c << 4) + k * 4);  // uniform
#pragma unroll
    for (int t = 0; t < 5; ++t) {
      const float* rp = base + t * HDIM + (c << 4);
      float4 v0 = *(const float4*)(rp + 0);  // 2-addr ds_read broadcast
      float4 v1 = *(const float4*)(rp + 4);
      float4 v2 = *(const float4*)(rp + 8);
      float4 v3 = *(const float4*)(rp + 12);
      accA[t] = g4pk8(spA[0], spA[1], wq[0], wq[1], v0, v1, accA[t]);
      accA[t] = g4pk8(spA[2], spA[3], wq[2], wq[3], v2, v3, accA[t]);
      accB[t] = g4pk8(spB[0], spB[1], wq[0], wq[1], v0, v1, accB[t]);
      accB[t] = g4pk8(spB[2], spB[3], wq[2], wq[3], v2, v3, accB[t]);
    }
  }
}

// Fused per 40-target tile, 256 threads. Same proven structure as R22,
// tile 32 -> 40 so grid = 500 blocks = 1.95/CU (balanced; was 625 = 2.44,
// 1.23x critical-path stretch). P1: emb tile -> LDS. P2: GEMM + exp2 ->
// et[40][128] LDS (thread = 5 rows x 4 h). P3: packed score5x2
// (lane&31 = session-pair, lane>>5 + wv*2 -> 5-target group).
// score[b][n] = C - 2 * sum_h w3[h] * rcp(fma(esp[b][h], etp[n][h], 1))
__global__ __launch_bounds__(256) void taa_fused(
    const float* __restrict__ emb, const float* __restrict__ W2,
    const float* __restrict__ b2, const float* __restrict__ esp4,
    const float* __restrict__ w3, const float* __restrict__ Cptr,
    float* __restrict__ out, int N) {
  __shared__ float sm[NT][132];       // emb tile, padded stride
  __shared__ float et[NT * HDIM];     // exp2(tp') tile
  const int nb = blockIdx.x * NT;

  // Phase 1: stage emb tile (coalesced float4, 5 per thread).
  for (int k = threadIdx.x; k < NT * 32; k += 256) {
    int r = k >> 5, c4 = k & 31;
    float4 v = make_float4(0.f, 0.f, 0.f, 0.f);
    if (nb + r < N) v = ((const float4*)(emb + (size_t)(nb + r) * EDIM))[c4];
    *(float4*)&sm[r][c4 * 4] = v;
  }
  __syncthreads();

  // Phase 2: GEMM + exp2 -> et (LDS). Thread = 5 rows x 4 h.
  {
    const int h4 = (threadIdx.x & 31) * 4;
    const int rg = threadIdx.x >> 5;  // 8 groups of 5 rows
    float acc[5][4];
#pragma unroll
    for (int j = 0; j < 5; ++j)
#pragma unroll
      for (int q = 0; q < 4; ++q) acc[j][q] = 0.f;
    for (int e = 0; e < EDIM; e += 4) {
      float4 w[4];
#pragma unroll
      for (int q = 0; q < 4; ++q)
        w[q] = *(const float4*)(W2 + (size_t)(e + q) * HDIM + h4);
#pragma unroll
      for (int j = 0; j < 5; ++j) {
        float4 em = *(const float4*)&sm[rg * 5 + j][e];
        acc[j][0] = fmaf(em.x, w[0].x, acc[j][0]);
        acc[j][1] = fmaf(em.x, w[0].y, acc[j][1]);
        acc[j][2] = fmaf(em.x, w[0].z, acc[j][2]);
        acc[j][3] = fmaf(em.x, w[0].w, acc[j][3]);
        acc[j][0] = fmaf(em.y, w[1].x, acc[j][0]);
        acc[j][1] = fmaf(em.y, w[1].y, acc[j][1]);
        acc[j][2] = fmaf(em.y, w[1].z, acc[j][2]);
        acc[j][3] = fmaf(em.y, w[1].w, acc[j][3]);
        acc[j][0] = fmaf(em.z, w[2].x, acc[j][0]);
        acc[j][1] = fmaf(em.z, w[2].y, acc[j][1]);
        acc[j][2] = fmaf(em.z, w[2].z, acc[j][2]);
        acc[j][3] = fmaf(em.z, w[2].w, acc[j][3]);
        acc[j][0] = fmaf(em.w, w[3].x, acc[j][0]);
        acc[j][1] = fmaf(em.w, w[3].y, acc[j][1]);
        acc[j][2] = fmaf(em.w, w[3].z, acc[j][2]);
        acc[j][3] = fmaf(em.w, w[3].w, acc[j][3]);
      }
    }
    float4 bb2 = *(const float4*)(b2 + h4);
#pragma unroll
    for (int j = 0; j < 5; ++j) {
      int nr = rg * 5 + j;
      float4 o;
      o.x = fexp2((acc[j][0] + bb2.x) * KSCALE);
      o.y = fexp2((acc[j][1] + bb2.y) * KSCALE);
      o.z = fexp2((acc[j][2] + bb2.z) * KSCALE);
      o.w = fexp2((acc[j][3] + bb2.w) * KSCALE);
      *(float4*)&et[nr * HDIM + h4] = o;  // wave-contiguous, conflict-free
    }
  }
  __syncthreads();

  // Phase 3: scoring. lane&31 = session-pair; (wv*2 + lane>>5) -> 5-target
  // group. Thread = 2 sessions x 5 targets.
  const int lane = threadIdx.x & 63;
  const int wv = threadIdx.x >> 6;  // 0..3
  const int sp2 = lane & 31;        // sessions 2*sp2, 2*sp2+1
  const int th = lane >> 5;
  const int t0 = (wv * 2 + th) * 5; // 0,5,...,35
  float accA[5] = {0.f, 0.f, 0.f, 0.f, 0.f};
  float accB[5] = {0.f, 0.f, 0.f, 0.f, 0.f};
  score5x2(et, t0, sp2, esp4, w3, accA, accB);

  const float Cv = *Cptr;  // uniform
  const int n0 = nb + t0;
  const int sA = sp2 * 2, sB = sA + 1;
  float* poA = out + (size_t)sA * N + n0;
  float* poB = out + (size_t)sB * N + n0;
#pragma unroll
  for (int t = 0; t < 5; ++t) {
    if (n0 + t < N) {
      poA[t] = fmaf(-2.f, accA[t], Cv);
      poB[t] = fmaf(-2.f, accB[t], Cv);
    }
  }
}

extern "C" void kernel_launch(void* const* d_in, const int* in_sizes, int n_in,
                              void* d_out, int out_size, void* d_ws, size_t ws_size,
                              hipStream_t stream) {
  const float* sess = (const float*)d_in[0];
  const float* emb  = (const float*)d_in[1];
  const float* W1   = (const float*)d_in[2];
  const float* b1   = (const float*)d_in[3];
  const float* W2   = (const float*)d_in[4];
  const float* b2   = (const float*)d_in[5];
  const float* W3   = (const float*)d_in[6];
  const float* b3   = (const float*)d_in[7];
  float* out = (float*)d_out;
  const int B = in_sizes[0] / EDIM;   // 64
  const int N = in_sizes[1] / EDIM;   // 20000

  float* esp4 = (float*)d_ws;                     // B*128 floats (packed)
  float* Cp   = esp4 + (size_t)BSES * HDIM;       // 1 float

  taa_esp<<<(B * HDIM + 255) / 256, 256, 0, stream>>>(sess, W1, b1, W3, b3,
                                                      esp4, Cp);
  taa_fused<<<(N + NT - 1) / NT, 256, 0, stream>>>(emb, W2, b2, esp4, W3, Cp,
                                                   out, N);
}